// Round 6
// baseline (162.823 us; speedup 1.0000x reference)
//
#include <hip/hip_runtime.h>

typedef __attribute__((ext_vector_type(8))) short short8v;
typedef __attribute__((ext_vector_type(4))) float f32x4;

#define NN 8192
#define HDIM 64
#define KDIM 128
#define LOG2E 1.44269504088896340736f

__device__ __forceinline__ unsigned short f2b(float f) {
    unsigned int u = __float_as_uint(f);
    return (unsigned short)((u + 0x7fffu + ((u >> 16) & 1u)) >> 16);
}

// ---------------- Kernel 1 (verified R3-R5): H = X@W, softmax row constants, HbT bf16 ----
__global__ __launch_bounds__(256) void gat_prep(
    const float* __restrict__ X, const float* __restrict__ W,
    const float* __restrict__ al, const float* __restrict__ ar,
    unsigned short* __restrict__ HbT, float* __restrict__ el2p,
    float* __restrict__ cpv, float* __restrict__ erp)
{
    __shared__ float Wl[KDIM * HDIM];
    const int t = threadIdx.x;
    {
        const float4* Wv = (const float4*)W;
        float4* Wlv = (float4*)Wl;
#pragma unroll
        for (int s = 0; s < 8; ++s) Wlv[t + s * 256] = Wv[t + s * 256];
    }
    __syncthreads();
    const int row = blockIdx.x * 32 + (t >> 3);
    const int cg = t & 7;
    const int c0 = cg * 8;
    float al8[8], ar8[8];
#pragma unroll
    for (int j = 0; j < 8; ++j) { al8[j] = al[c0 + j]; ar8[j] = ar[c0 + j]; }
    float acc[8];
#pragma unroll
    for (int j = 0; j < 8; ++j) acc[j] = 0.f;
    const float4* Xv = (const float4*)(X + row * KDIM);
    for (int k4 = 0; k4 < 32; ++k4) {
        float4 x4 = Xv[k4];
        float xs[4] = {x4.x, x4.y, x4.z, x4.w};
#pragma unroll
        for (int kk = 0; kk < 4; ++kk) {
            const int k = k4 * 4 + kk;
            const float x = xs[kk];
            const float4 w0 = *(const float4*)&Wl[k * HDIM + c0];
            const float4 w1 = *(const float4*)&Wl[k * HDIM + c0 + 4];
            acc[0] = fmaf(x, w0.x, acc[0]); acc[1] = fmaf(x, w0.y, acc[1]);
            acc[2] = fmaf(x, w0.z, acc[2]); acc[3] = fmaf(x, w0.w, acc[3]);
            acc[4] = fmaf(x, w1.x, acc[4]); acc[5] = fmaf(x, w1.y, acc[5]);
            acc[6] = fmaf(x, w1.z, acc[6]); acc[7] = fmaf(x, w1.w, acc[7]);
        }
    }
    float pl = 0.f, pr = 0.f;
#pragma unroll
    for (int j = 0; j < 8; ++j) {
        pl = fmaf(acc[j], al8[j], pl);
        pr = fmaf(acc[j], ar8[j], pr);
    }
    pl += __shfl_xor(pl, 1, 64); pl += __shfl_xor(pl, 2, 64); pl += __shfl_xor(pl, 4, 64);
    pr += __shfl_xor(pr, 1, 64); pr += __shfl_xor(pr, 2, 64); pr += __shfl_xor(pr, 4, 64);
    if (cg == 0) {
        const float el = pl;
        // m_i = leaky(e_l + 8): row upper bound; softmax shift-invariance makes it EXACT.
        const float s8 = el + 8.0f;
        const float m = fmaxf(s8, 0.2f * s8);
        el2p[row] = (el - m) * LOG2E;
        cpv[row] = -0.8f * m * LOG2E;
        erp[row] = pr * LOG2E;
    }
#pragma unroll
    for (int j = 0; j < 8; ++j) HbT[(c0 + j) * NN + row] = f2b(acc[j]);
}

// ---------------- Kernel 2: wave-independent scatter, 4096 waves, 4 waves/SIMD. -----
// Wave owns 16 rows x 1024 cols. Swapped MFMA C^T = H^T . p^T keeps p lane-local.
// Rowsum via 5th MFMA with all-ones A-fragment (denominator == numerator arithmetic).
__global__ __launch_bounds__(256, 4) void gat_scatter(
    const int* __restrict__ A, const unsigned short* __restrict__ HbT,
    const float* __restrict__ el2p, const float* __restrict__ cpv,
    const float* __restrict__ erp, float* __restrict__ out, float* __restrict__ dsum)
{
    const int t = threadIdx.x;
    const int l = t & 63;
    const int wid = blockIdx.x * 4 + (t >> 6);   // 0..4095
    const int rowbase = (wid >> 3) * 16;
    const long jqb = (long)(wid & 7) * 1024;
    const int l15 = l & 15, lq = l >> 4;
    const int row = rowbase + l15;
    const float el2c = el2p[row], cpc = cpv[row];
    const int* Arow = A + (long)row * NN + jqb + lq * 8;
    const float* erb = erp + jqb + lq * 8;
    const unsigned short* Hb = HbT + (long)l15 * NN + jqb + lq * 8;

    f32x4 acc0 = {0,0,0,0}, acc1 = {0,0,0,0}, acc2 = {0,0,0,0}, acc3 = {0,0,0,0};
    f32x4 accs = {0,0,0,0}; // rowsum accumulator (ones-MFMA)
    union { unsigned short s[8]; short8v v; } ones;
#pragma unroll
    for (int i = 0; i < 8; ++i) ones.s[i] = 0x3F80; // bf16 1.0

    int4 bufA[8], bufB[8]; // group = 4 chunks x 128 cols; 2 int4 per chunk per lane

    auto loadG = [&](int4* buf, int g) {
        const int4* p = (const int4*)(Arow + (long)g * 128);
#pragma unroll
        for (int kc = 0; kc < 4; ++kc) {
            buf[2 * kc] = p[kc * 8];
            buf[2 * kc + 1] = p[kc * 8 + 1];
        }
    };

    auto doG = [&](const int4* buf, int g) {
#pragma unroll
        for (int kc = 0; kc < 4; ++kc) {
            const int cb = g * 128 + kc * 32;
            const float4 e0 = *(const float4*)(erb + cb);
            const float4 e1 = *(const float4*)(erb + cb + 4);
            const int am[8] = {buf[2*kc].x, buf[2*kc].y, buf[2*kc].z, buf[2*kc].w,
                               buf[2*kc+1].x, buf[2*kc+1].y, buf[2*kc+1].z, buf[2*kc+1].w};
            const float ev[8] = {e0.x, e0.y, e0.z, e0.w, e1.x, e1.y, e1.z, e1.w};
            union { unsigned int u[4]; short8v v; } pu;
#pragma unroll
            for (int h = 0; h < 4; ++h) {
                const float u0 = el2c + ev[2 * h];
                const float v0 = fmaf(u0, 0.2f, cpc);
                float g0 = fmaxf(u0, v0);
                g0 = am[2 * h] ? g0 : -1e30f;
                const float p0 = exp2f(g0);
                const float u1 = el2c + ev[2 * h + 1];
                const float v1 = fmaf(u1, 0.2f, cpc);
                float g1 = fmaxf(u1, v1);
                g1 = am[2 * h + 1] ? g1 : -1e30f;
                const float p1 = exp2f(g1);
                // D[15:0] = cvt(src0)=p0, D[31:16] = cvt(src1)=p1 -> matches k-order
                asm("v_cvt_pk_bf16_f32 %0, %1, %2" : "=v"(pu.u[h]) : "v"(p0), "v"(p1));
            }
            const unsigned short* hp = Hb + cb;
            const short8v h0 = *(const short8v*)(hp);
            const short8v h1 = *(const short8v*)(hp + 16 * NN);
            const short8v h2 = *(const short8v*)(hp + 32 * NN);
            const short8v h3 = *(const short8v*)(hp + 48 * NN);
            acc0 = __builtin_amdgcn_mfma_f32_16x16x32_bf16(h0, pu.v, acc0, 0, 0, 0);
            acc1 = __builtin_amdgcn_mfma_f32_16x16x32_bf16(h1, pu.v, acc1, 0, 0, 0);
            acc2 = __builtin_amdgcn_mfma_f32_16x16x32_bf16(h2, pu.v, acc2, 0, 0, 0);
            acc3 = __builtin_amdgcn_mfma_f32_16x16x32_bf16(h3, pu.v, acc3, 0, 0, 0);
            accs = __builtin_amdgcn_mfma_f32_16x16x32_bf16(ones.v, pu.v, accs, 0, 0, 0);
        }
    };

    // 8 groups of 128 cols, 2-group-deep register pipeline
    loadG(bufA, 0);
    loadG(bufB, 1);
    doG(bufA, 0);
    loadG(bufA, 2);
    doG(bufB, 1);
    loadG(bufB, 3);
    doG(bufA, 2);
    loadG(bufA, 4);
    doG(bufB, 3);
    loadG(bufB, 5);
    doG(bufA, 4);
    loadG(bufA, 6);
    doG(bufB, 5);
    loadG(bufB, 7);
    doG(bufA, 6);
    doG(bufB, 7);

    // denominator partial: accs[r] = rowsum[l15] (replicated over r and lq)
    if (l < 16) atomicAdd(dsum + row, accs[0]);

    // numerator partial: acc_nt[r] = (p.H)[row=l15][col=nt*16+lq*4+r]
    float* ob = out + (long)row * HDIM + lq * 4;
#pragma unroll
    for (int r = 0; r < 4; ++r) {
        atomicAdd(ob + 0 + r, acc0[r]);
        atomicAdd(ob + 16 + r, acc1[r]);
        atomicAdd(ob + 32 + r, acc2[r]);
        atomicAdd(ob + 48 + r, acc3[r]);
    }
}

// ---------------- Kernel 3: out *= 1/dsum[row] ------------------------------------
__global__ __launch_bounds__(256) void gat_norm(float* __restrict__ out,
                                                const float* __restrict__ dsum)
{
    const int i4 = blockIdx.x * 256 + threadIdx.x; // float4 index; 16 per row
    float4 v = ((float4*)out)[i4];
    const float ri = 1.0f / dsum[i4 >> 4];
    v.x *= ri; v.y *= ri; v.z *= ri; v.w *= ri;
    ((float4*)out)[i4] = v;
}

extern "C" void kernel_launch(void* const* d_in, const int* in_sizes, int n_in,
                              void* d_out, int out_size, void* d_ws, size_t ws_size,
                              hipStream_t stream) {
    const float *X = nullptr, *W = nullptr, *al = nullptr, *ar = nullptr;
    const int* A = nullptr;
    for (int i = 0; i < n_in; ++i) {
        const long s = in_sizes[i];
        if (s == (long)NN * NN) A = (const int*)d_in[i];
        else if (s == (long)NN * KDIM) X = (const float*)d_in[i];
        else if (s == (long)KDIM * HDIM) W = (const float*)d_in[i];
        else if (s == HDIM) { if (!al) al = (const float*)d_in[i]; else ar = (const float*)d_in[i]; }
    }
    float* out = (float*)d_out;
    // ws: HbT (1MB) + el2p/cpv/erp/dsum (4 x 32KB)
    unsigned short* HbT = (unsigned short*)d_ws;
    float* el2p = (float*)((char*)d_ws + (long)NN * HDIM * 2);
    float* cpv = el2p + NN;
    float* erp = cpv + NN;
    float* dsum = erp + NN;
    hipMemsetAsync(d_out, 0, (long)NN * HDIM * sizeof(float), stream);
    hipMemsetAsync(dsum, 0, NN * sizeof(float), stream);
    hipLaunchKernelGGL(gat_prep, dim3(256), dim3(256), 0, stream, X, W, al, ar, HbT, el2p, cpv, erp);
    hipLaunchKernelGGL(gat_scatter, dim3(1024), dim3(256), 0, stream, A, HbT, el2p, cpv, erp, out, dsum);
    hipLaunchKernelGGL(gat_norm, dim3(512), dim3(256), 0, stream, out, dsum);
}

// Round 7
// 146.333 us; speedup vs baseline: 1.1127x; 1.1127x over previous
//
#include <hip/hip_runtime.h>

typedef __attribute__((ext_vector_type(8))) short short8v;
typedef __attribute__((ext_vector_type(4))) float f32x4;

#define NN 8192
#define HDIM 64
#define KDIM 128
#define LOG2E 1.44269504088896340736f

typedef const void __attribute__((address_space(1)))* gas_cvp;
typedef void __attribute__((address_space(3)))* las_vp;

#define PIN() asm volatile("" ::: "memory")

__device__ __forceinline__ unsigned short f2b(float f) {
    unsigned int u = __float_as_uint(f);
    return (unsigned short)((u + 0x7fffu + ((u >> 16) & 1u)) >> 16);
}

// ---------------- Kernel 1 (verified R3-R6): H = X@W, softmax row constants, HbT bf16 ----
__global__ __launch_bounds__(256) void gat_prep(
    const float* __restrict__ X, const float* __restrict__ W,
    const float* __restrict__ al, const float* __restrict__ ar,
    unsigned short* __restrict__ HbT, float* __restrict__ el2p,
    float* __restrict__ cpv, float* __restrict__ erp)
{
    __shared__ float Wl[KDIM * HDIM];
    const int t = threadIdx.x;
    {
        const float4* Wv = (const float4*)W;
        float4* Wlv = (float4*)Wl;
#pragma unroll
        for (int s = 0; s < 8; ++s) Wlv[t + s * 256] = Wv[t + s * 256];
    }
    __syncthreads();
    const int row = blockIdx.x * 32 + (t >> 3);
    const int cg = t & 7;
    const int c0 = cg * 8;
    float al8[8], ar8[8];
#pragma unroll
    for (int j = 0; j < 8; ++j) { al8[j] = al[c0 + j]; ar8[j] = ar[c0 + j]; }
    float acc[8];
#pragma unroll
    for (int j = 0; j < 8; ++j) acc[j] = 0.f;
    const float4* Xv = (const float4*)(X + row * KDIM);
    for (int k4 = 0; k4 < 32; ++k4) {
        float4 x4 = Xv[k4];
        float xs[4] = {x4.x, x4.y, x4.z, x4.w};
#pragma unroll
        for (int kk = 0; kk < 4; ++kk) {
            const int k = k4 * 4 + kk;
            const float x = xs[kk];
            const float4 w0 = *(const float4*)&Wl[k * HDIM + c0];
            const float4 w1 = *(const float4*)&Wl[k * HDIM + c0 + 4];
            acc[0] = fmaf(x, w0.x, acc[0]); acc[1] = fmaf(x, w0.y, acc[1]);
            acc[2] = fmaf(x, w0.z, acc[2]); acc[3] = fmaf(x, w0.w, acc[3]);
            acc[4] = fmaf(x, w1.x, acc[4]); acc[5] = fmaf(x, w1.y, acc[5]);
            acc[6] = fmaf(x, w1.z, acc[6]); acc[7] = fmaf(x, w1.w, acc[7]);
        }
    }
    float pl = 0.f, pr = 0.f;
#pragma unroll
    for (int j = 0; j < 8; ++j) {
        pl = fmaf(acc[j], al8[j], pl);
        pr = fmaf(acc[j], ar8[j], pr);
    }
    pl += __shfl_xor(pl, 1, 64); pl += __shfl_xor(pl, 2, 64); pl += __shfl_xor(pl, 4, 64);
    pr += __shfl_xor(pr, 1, 64); pr += __shfl_xor(pr, 2, 64); pr += __shfl_xor(pr, 4, 64);
    if (cg == 0) {
        const float el = pl;
        // m_i = leaky(e_l + 8): row upper bound; softmax shift-invariance makes it EXACT.
        const float s8 = el + 8.0f;
        const float m = fmaxf(s8, 0.2f * s8);
        el2p[row] = (el - m) * LOG2E;
        cpv[row] = -0.8f * m * LOG2E;
        erp[row] = pr * LOG2E;
    }
#pragma unroll
    for (int j = 0; j < 8; ++j) HbT[(c0 + j) * NN + row] = f2b(acc[j]);
}

// ---------------- Kernel 2: wave-independent scatter with PINNED prefetch pipeline ----
// 4096 waves, wave owns 16 rows x 1024 cols (32 chunks of 32 cols).
// A: 3-slot register ring, issued 2 chunks ahead. H: double buffer, 1 ahead.
// e_r slice: staged once to LDS via global_load_lds, ds_read per chunk.
// asm memory pins prevent the scheduler from collapsing the pipeline.
__global__ __launch_bounds__(256, 4) void gat_scatter(
    const int* __restrict__ A, const unsigned short* __restrict__ HbT,
    const float* __restrict__ el2p, const float* __restrict__ cpv,
    const float* __restrict__ erp, float* __restrict__ out, float* __restrict__ dsum)
{
    __shared__ float e_smem[4][1024]; // 4 KB per wave
    const int t = threadIdx.x;
    const int l = t & 63;
    const int w = t >> 6;
    const int wid = blockIdx.x * 4 + w;          // 0..4095
    const int rowbase = (wid >> 3) * 16;
    const long jqb = (long)(wid & 7) * 1024;
    const int l15 = l & 15, lq = l >> 4;
    const int row = rowbase + l15;
    const float el2c = el2p[row], cpc = cpv[row];
    const int* Arow = A + (long)row * NN + jqb + lq * 8;
    const unsigned short* Hb = HbT + (long)l15 * NN + jqb + lq * 8;
    float* e_lds = e_smem[w];

    // ---- prologue: stage e_r slice (1024 f32) to LDS via DMA, drain once ----
#pragma unroll
    for (int q = 0; q < 4; ++q) {
        __builtin_amdgcn_global_load_lds((gas_cvp)(erp + jqb + q * 256 + l * 4),
                                         (las_vp)(e_lds + q * 256), 16, 0, 0);
    }
    asm volatile("s_waitcnt vmcnt(0)" ::: "memory");

    f32x4 acc0 = {0,0,0,0}, acc1 = {0,0,0,0}, acc2 = {0,0,0,0}, acc3 = {0,0,0,0};
    f32x4 accs = {0,0,0,0};
    union { unsigned short s[8]; short8v v; } ones;
#pragma unroll
    for (int i = 0; i < 8; ++i) ones.s[i] = 0x3F80; // bf16 1.0

    int4 Aq0[3], Aq1[3];      // 3-slot A ring (slot = c % 3)
    short8v Hh[2][4];         // H double buffer (buf = c & 1)

    // ---- prologue issues: A(0), A(1), H(0) ----
    Aq0[0] = *(const int4*)(Arow);           Aq1[0] = *(const int4*)(Arow + 4);
    Aq0[1] = *(const int4*)(Arow + 32);      Aq1[1] = *(const int4*)(Arow + 36);
#pragma unroll
    for (int q = 0; q < 4; ++q) Hh[0][q] = *(const short8v*)(Hb + q * 16 * NN);
    PIN();

#pragma unroll
    for (int c = 0; c < 32; ++c) {
        // ---- issue group: A 2 ahead, H 1 ahead ----
        if (c + 2 < 32) {
            Aq0[(c + 2) % 3] = *(const int4*)(Arow + (c + 2) * 32);
            Aq1[(c + 2) % 3] = *(const int4*)(Arow + (c + 2) * 32 + 4);
        }
        if (c + 1 < 32) {
#pragma unroll
            for (int q = 0; q < 4; ++q)
                Hh[(c + 1) & 1][q] = *(const short8v*)(Hb + q * 16 * NN + (c + 1) * 32);
        }
        PIN(); // loads above may not sink below this point

        // ---- compute chunk c ----
        const float4 e0 = *(const float4*)(e_lds + c * 32 + lq * 8);
        const float4 e1 = *(const float4*)(e_lds + c * 32 + lq * 8 + 4);
        const int4 a0 = Aq0[c % 3];
        const int4 a1 = Aq1[c % 3];
        const int am[8] = {a0.x, a0.y, a0.z, a0.w, a1.x, a1.y, a1.z, a1.w};
        const float ev[8] = {e0.x, e0.y, e0.z, e0.w, e1.x, e1.y, e1.z, e1.w};
        union { unsigned int u[4]; short8v v; } pu;
#pragma unroll
        for (int h = 0; h < 4; ++h) {
            const float u0 = el2c + ev[2 * h];
            const float v0 = fmaf(u0, 0.2f, cpc);
            float g0 = fmaxf(u0, v0);
            g0 = am[2 * h] ? g0 : -1e30f;
            const float p0 = exp2f(g0);
            const float u1 = el2c + ev[2 * h + 1];
            const float v1 = fmaf(u1, 0.2f, cpc);
            float g1 = fmaxf(u1, v1);
            g1 = am[2 * h + 1] ? g1 : -1e30f;
            const float p1 = exp2f(g1);
            asm("v_cvt_pk_bf16_f32 %0, %1, %2" : "=v"(pu.u[h]) : "v"(p0), "v"(p1));
        }
        acc0 = __builtin_amdgcn_mfma_f32_16x16x32_bf16(Hh[c & 1][0], pu.v, acc0, 0, 0, 0);
        acc1 = __builtin_amdgcn_mfma_f32_16x16x32_bf16(Hh[c & 1][1], pu.v, acc1, 0, 0, 0);
        acc2 = __builtin_amdgcn_mfma_f32_16x16x32_bf16(Hh[c & 1][2], pu.v, acc2, 0, 0, 0);
        acc3 = __builtin_amdgcn_mfma_f32_16x16x32_bf16(Hh[c & 1][3], pu.v, acc3, 0, 0, 0);
        accs = __builtin_amdgcn_mfma_f32_16x16x32_bf16(ones.v, pu.v, accs, 0, 0, 0);
    }

    // denominator partial: accs[r] = rowsum[l15] (replicated over r and lq)
    if (l < 16) atomicAdd(dsum + row, accs[0]);

    // numerator partial: acc_nt[r] = (p.H)[row=l15][col=nt*16+lq*4+r]
    float* ob = out + (long)row * HDIM + lq * 4;
#pragma unroll
    for (int r = 0; r < 4; ++r) {
        atomicAdd(ob + 0 + r, acc0[r]);
        atomicAdd(ob + 16 + r, acc1[r]);
        atomicAdd(ob + 32 + r, acc2[r]);
        atomicAdd(ob + 48 + r, acc3[r]);
    }
}

// ---------------- Kernel 3: out *= 1/dsum[row] ------------------------------------
__global__ __launch_bounds__(256) void gat_norm(float* __restrict__ out,
                                                const float* __restrict__ dsum)
{
    const int i4 = blockIdx.x * 256 + threadIdx.x; // float4 index; 16 per row
    float4 v = ((float4*)out)[i4];
    const float ri = 1.0f / dsum[i4 >> 4];
    v.x *= ri; v.y *= ri; v.z *= ri; v.w *= ri;
    ((float4*)out)[i4] = v;
}

extern "C" void kernel_launch(void* const* d_in, const int* in_sizes, int n_in,
                              void* d_out, int out_size, void* d_ws, size_t ws_size,
                              hipStream_t stream) {
    const float *X = nullptr, *W = nullptr, *al = nullptr, *ar = nullptr;
    const int* A = nullptr;
    for (int i = 0; i < n_in; ++i) {
        const long s = in_sizes[i];
        if (s == (long)NN * NN) A = (const int*)d_in[i];
        else if (s == (long)NN * KDIM) X = (const float*)d_in[i];
        else if (s == (long)KDIM * HDIM) W = (const float*)d_in[i];
        else if (s == HDIM) { if (!al) al = (const float*)d_in[i]; else ar = (const float*)d_in[i]; }
    }
    float* out = (float*)d_out;
    // ws: HbT (1MB) + el2p/cpv/erp/dsum (4 x 32KB)
    unsigned short* HbT = (unsigned short*)d_ws;
    float* el2p = (float*)((char*)d_ws + (long)NN * HDIM * 2);
    float* cpv = el2p + NN;
    float* erp = cpv + NN;
    float* dsum = erp + NN;
    hipMemsetAsync(d_out, 0, (long)NN * HDIM * sizeof(float), stream);
    hipMemsetAsync(dsum, 0, NN * sizeof(float), stream);
    hipLaunchKernelGGL(gat_prep, dim3(256), dim3(256), 0, stream, X, W, al, ar, HbT, el2p, cpv, erp);
    hipLaunchKernelGGL(gat_scatter, dim3(1024), dim3(256), 0, stream, A, HbT, el2p, cpv, erp, out, dsum);
    hipLaunchKernelGGL(gat_norm, dim3(512), dim3(256), 0, stream, out, dsum);
}

// Round 8
// 132.690 us; speedup vs baseline: 1.2271x; 1.1028x over previous
//
#include <hip/hip_runtime.h>

typedef __attribute__((ext_vector_type(8))) short short8v;
typedef __attribute__((ext_vector_type(4))) float f32x4;
typedef __attribute__((ext_vector_type(2))) unsigned int uint2v;

#define NN 8192
#define HDIM 64
#define KDIM 128
#define LOG2E 1.44269504088896340736f

__device__ __forceinline__ unsigned short f2b(float f) {
    unsigned int u = __float_as_uint(f);
    return (unsigned short)((u + 0x7fffu + ((u >> 16) & 1u)) >> 16);
}
__device__ __forceinline__ float b2f(unsigned short s) {
    return __uint_as_float(((unsigned int)s) << 16);
}

// ---------------- Kernel 1 (verified R3-R7): H = X@W, softmax row constants, HbT bf16 ----
__global__ __launch_bounds__(256) void gat_prep(
    const float* __restrict__ X, const float* __restrict__ W,
    const float* __restrict__ al, const float* __restrict__ ar,
    unsigned short* __restrict__ HbT, float* __restrict__ el2p,
    float* __restrict__ cpv, float* __restrict__ erp)
{
    __shared__ float Wl[KDIM * HDIM];
    const int t = threadIdx.x;
    {
        const float4* Wv = (const float4*)W;
        float4* Wlv = (float4*)Wl;
#pragma unroll
        for (int s = 0; s < 8; ++s) Wlv[t + s * 256] = Wv[t + s * 256];
    }
    __syncthreads();
    const int row = blockIdx.x * 32 + (t >> 3);
    const int cg = t & 7;
    const int c0 = cg * 8;
    float al8[8], ar8[8];
#pragma unroll
    for (int j = 0; j < 8; ++j) { al8[j] = al[c0 + j]; ar8[j] = ar[c0 + j]; }
    float acc[8];
#pragma unroll
    for (int j = 0; j < 8; ++j) acc[j] = 0.f;
    const float4* Xv = (const float4*)(X + row * KDIM);
    for (int k4 = 0; k4 < 32; ++k4) {
        float4 x4 = Xv[k4];
        float xs[4] = {x4.x, x4.y, x4.z, x4.w};
#pragma unroll
        for (int kk = 0; kk < 4; ++kk) {
            const int k = k4 * 4 + kk;
            const float x = xs[kk];
            const float4 w0 = *(const float4*)&Wl[k * HDIM + c0];
            const float4 w1 = *(const float4*)&Wl[k * HDIM + c0 + 4];
            acc[0] = fmaf(x, w0.x, acc[0]); acc[1] = fmaf(x, w0.y, acc[1]);
            acc[2] = fmaf(x, w0.z, acc[2]); acc[3] = fmaf(x, w0.w, acc[3]);
            acc[4] = fmaf(x, w1.x, acc[4]); acc[5] = fmaf(x, w1.y, acc[5]);
            acc[6] = fmaf(x, w1.z, acc[6]); acc[7] = fmaf(x, w1.w, acc[7]);
        }
    }
    float pl = 0.f, pr = 0.f;
#pragma unroll
    for (int j = 0; j < 8; ++j) {
        pl = fmaf(acc[j], al8[j], pl);
        pr = fmaf(acc[j], ar8[j], pr);
    }
    pl += __shfl_xor(pl, 1, 64); pl += __shfl_xor(pl, 2, 64); pl += __shfl_xor(pl, 4, 64);
    pr += __shfl_xor(pr, 1, 64); pr += __shfl_xor(pr, 2, 64); pr += __shfl_xor(pr, 4, 64);
    if (cg == 0) {
        const float el = pl;
        // m_i = leaky(e_l + 8): row upper bound; softmax shift-invariance makes it EXACT.
        const float s8 = el + 8.0f;
        const float m = fmaxf(s8, 0.2f * s8);
        el2p[row] = (el - m) * LOG2E;
        cpv[row] = -0.8f * m * LOG2E;
        erp[row] = pr * LOG2E;
    }
#pragma unroll
    for (int j = 0; j < 8; ++j) HbT[(c0 + j) * NN + row] = f2b(acc[j]);
}

// ---------------- Kernel 2: R4 inner loop, 4-way j-split -> 4 blocks/CU ----------
// grid 1024 x 512; block = 32 rows x 2048 cols (8 tiles of 256), atomic combine.
__global__ __launch_bounds__(512) void gat_main(
    const int* __restrict__ A, const unsigned short* __restrict__ HbT,
    const float* __restrict__ el2p, const float* __restrict__ cpv,
    const float* __restrict__ erp, float* __restrict__ out, float* __restrict__ dsum)
{
    __shared__ unsigned short plds[2][32 * 264]; // bf16 p, row stride 264
    const int t = threadIdx.x;
    const int l = t & 63;
    const int w = t >> 6;
    const int rowbase = (blockIdx.x >> 2) * 32;
    const int jq8 = (blockIdx.x & 3) * 8;        // first of 8 owned 256-col tiles
    const int l15 = l & 15, lq = l >> 4;

    float el2c[4], cpc[4];
    const int4* Ap[4];
#pragma unroll
    for (int i = 0; i < 4; ++i) {
        const int gr = rowbase + 8 * i + w;
        el2c[i] = el2p[gr];
        cpc[i] = cpv[gr];
        Ap[i] = (const int4*)(A + (long)gr * NN + 4 * l);
    }
    float rsum[4] = {0.f, 0.f, 0.f, 0.f};
    f32x4 acc = {0.f, 0.f, 0.f, 0.f};
    const int mh = w >> 2, nq = w & 3;
    const unsigned short* bbase = HbT + (long)(nq * 16 + l15) * NN + lq * 8;
    const int aoff = (mh * 16 + l15) * 264 + lq * 8;

    int4 A0[4], A1[4];
    float4 E0, E1;

    auto loadT = [&](int4* av, float4& e4, int jt) {
        const int jb4 = jt * 64;
#pragma unroll
        for (int i = 0; i < 4; ++i) av[i] = Ap[i][jb4];
        e4 = *(const float4*)(erp + jt * 256 + 4 * l);
    };

    auto phase1 = [&](const int4* av, const float4 e4, unsigned short* buf) {
        const float e[4] = {e4.x, e4.y, e4.z, e4.w};
#pragma unroll
        for (int i = 0; i < 4; ++i) {
            const int am[4] = {av[i].x, av[i].y, av[i].z, av[i].w};
            unsigned short b[4];
#pragma unroll
            for (int c = 0; c < 4; ++c) {
                const float u = el2c[i] + e[c];
                const float v = fmaf(u, 0.2f, cpc[i]);
                float g = fmaxf(u, v);
                g = am[c] ? g : -1e30f; // non-edge -> exp2 -> 0
                const float pp = exp2f(g);
                b[c] = f2b(pp);
                rsum[i] += b2f(b[c]); // denominator from ROUNDED p (matches numerator)
            }
            const unsigned int lo = (unsigned int)b[0] | ((unsigned int)b[1] << 16);
            const unsigned int hi = (unsigned int)b[2] | ((unsigned int)b[3] << 16);
            *(uint2v*)(buf + (8 * i + w) * 264 + 4 * l) = (uint2v){lo, hi};
        }
    };

    auto mfmaT = [&](const unsigned short* buf, long jbase) {
        const unsigned short* bp = bbase + jbase;
#pragma unroll
        for (int kc = 0; kc < 8; ++kc) {
            short8v af = *(const short8v*)(buf + aoff + kc * 32);
            short8v bf = *(const short8v*)(bp + kc * 32);
            acc = __builtin_amdgcn_mfma_f32_16x16x32_bf16(af, bf, acc, 0, 0, 0);
        }
    };

    loadT(A0, E0, jq8);
    loadT(A1, E1, jq8 + 1);
#pragma unroll
    for (int s = 0; s < 4; ++s) {
        const int jt = jq8 + 2 * s;
        phase1(A0, E0, plds[0]);
        if (s < 3) loadT(A0, E0, jt + 2); // prefetch 2 tiles ahead
        __syncthreads();
        mfmaT(plds[0], (long)jt * 256);
        phase1(A1, E1, plds[1]);
        if (s < 3) loadT(A1, E1, jt + 3);
        __syncthreads();
        mfmaT(plds[1], (long)(jt + 1) * 256);
    }

    // denominator partials: all 64 lanes hold disjoint-j partials of row 8i+w
#pragma unroll
    for (int i = 0; i < 4; ++i) {
        float v = rsum[i];
#pragma unroll
        for (int off = 32; off > 0; off >>= 1) v += __shfl_xor(v, off, 64);
        if (l == 0) atomicAdd(dsum + rowbase + 8 * i + w, v);
    }
    // numerator partials
#pragma unroll
    for (int r = 0; r < 4; ++r) {
        const int row = mh * 16 + lq * 4 + r; // D layout: col=lane&15, row=(lane>>4)*4+r
        atomicAdd(out + (long)(rowbase + row) * HDIM + nq * 16 + l15, acc[r]);
    }
}

// ---------------- Kernel 3: out *= 1/dsum[row] ------------------------------------
__global__ __launch_bounds__(256) void gat_norm(float* __restrict__ out,
                                                const float* __restrict__ dsum)
{
    const int i4 = blockIdx.x * 256 + threadIdx.x; // float4 index; 16 per row
    float4 v = ((float4*)out)[i4];
    const float ri = 1.0f / dsum[i4 >> 4];
    v.x *= ri; v.y *= ri; v.z *= ri; v.w *= ri;
    ((float4*)out)[i4] = v;
}

extern "C" void kernel_launch(void* const* d_in, const int* in_sizes, int n_in,
                              void* d_out, int out_size, void* d_ws, size_t ws_size,
                              hipStream_t stream) {
    const float *X = nullptr, *W = nullptr, *al = nullptr, *ar = nullptr;
    const int* A = nullptr;
    for (int i = 0; i < n_in; ++i) {
        const long s = in_sizes[i];
        if (s == (long)NN * NN) A = (const int*)d_in[i];
        else if (s == (long)NN * KDIM) X = (const float*)d_in[i];
        else if (s == (long)KDIM * HDIM) W = (const float*)d_in[i];
        else if (s == HDIM) { if (!al) al = (const float*)d_in[i]; else ar = (const float*)d_in[i]; }
    }
    float* out = (float*)d_out;
    // ws: HbT (1MB) + el2p/cpv/erp/dsum (4 x 32KB)
    unsigned short* HbT = (unsigned short*)d_ws;
    float* el2p = (float*)((char*)d_ws + (long)NN * HDIM * 2);
    float* cpv = el2p + NN;
    float* erp = cpv + NN;
    float* dsum = erp + NN;
    hipMemsetAsync(d_out, 0, (long)NN * HDIM * sizeof(float), stream);
    hipMemsetAsync(dsum, 0, NN * sizeof(float), stream);
    hipLaunchKernelGGL(gat_prep, dim3(256), dim3(256), 0, stream, X, W, al, ar, HbT, el2p, cpv, erp);
    hipLaunchKernelGGL(gat_main, dim3(1024), dim3(512), 0, stream, A, HbT, el2p, cpv, erp, out, dsum);
    hipLaunchKernelGGL(gat_norm, dim3(512), dim3(256), 0, stream, out, dsum);
}

// Round 9
// 103.263 us; speedup vs baseline: 1.5768x; 1.2850x over previous
//
#include <hip/hip_runtime.h>

typedef __attribute__((ext_vector_type(8))) short short8v;
typedef __attribute__((ext_vector_type(4))) float f32x4;
typedef __attribute__((ext_vector_type(2))) unsigned int uint2v;

#define NN 8192
#define HDIM 64
#define KDIM 128
#define LOG2E 1.44269504088896340736f

#define PIN() asm volatile("" ::: "memory")
// Barrier WITHOUT vmcnt drain: LDS hazards need only lgkmcnt(0).
// (ds_writes complete before barrier; ds_reads of the outgoing buffer are also
//  lgkm-drained, so the next phase's writes to the other buffer are WAR-safe.)
#define BAR() asm volatile("s_waitcnt lgkmcnt(0)\n\ts_barrier" ::: "memory")

__device__ __forceinline__ unsigned short f2b(float f) {
    unsigned int u = __float_as_uint(f);
    return (unsigned short)((u + 0x7fffu + ((u >> 16) & 1u)) >> 16);
}

// ---------------- Kernel 1 (verified R3-R8): H = X@W, softmax row constants, HbT bf16 ----
__global__ __launch_bounds__(256) void gat_prep(
    const float* __restrict__ X, const float* __restrict__ W,
    const float* __restrict__ al, const float* __restrict__ ar,
    unsigned short* __restrict__ HbT, float* __restrict__ el2p,
    float* __restrict__ cpv, float* __restrict__ erp)
{
    __shared__ float Wl[KDIM * HDIM];
    const int t = threadIdx.x;
    {
        const float4* Wv = (const float4*)W;
        float4* Wlv = (float4*)Wl;
#pragma unroll
        for (int s = 0; s < 8; ++s) Wlv[t + s * 256] = Wv[t + s * 256];
    }
    __syncthreads();
    const int row = blockIdx.x * 32 + (t >> 3);
    const int cg = t & 7;
    const int c0 = cg * 8;
    float al8[8], ar8[8];
#pragma unroll
    for (int j = 0; j < 8; ++j) { al8[j] = al[c0 + j]; ar8[j] = ar[c0 + j]; }
    float acc[8];
#pragma unroll
    for (int j = 0; j < 8; ++j) acc[j] = 0.f;
    const float4* Xv = (const float4*)(X + row * KDIM);
    for (int k4 = 0; k4 < 32; ++k4) {
        float4 x4 = Xv[k4];
        float xs[4] = {x4.x, x4.y, x4.z, x4.w};
#pragma unroll
        for (int kk = 0; kk < 4; ++kk) {
            const int k = k4 * 4 + kk;
            const float x = xs[kk];
            const float4 w0 = *(const float4*)&Wl[k * HDIM + c0];
            const float4 w1 = *(const float4*)&Wl[k * HDIM + c0 + 4];
            acc[0] = fmaf(x, w0.x, acc[0]); acc[1] = fmaf(x, w0.y, acc[1]);
            acc[2] = fmaf(x, w0.z, acc[2]); acc[3] = fmaf(x, w0.w, acc[3]);
            acc[4] = fmaf(x, w1.x, acc[4]); acc[5] = fmaf(x, w1.y, acc[5]);
            acc[6] = fmaf(x, w1.z, acc[6]); acc[7] = fmaf(x, w1.w, acc[7]);
        }
    }
    float pl = 0.f, pr = 0.f;
#pragma unroll
    for (int j = 0; j < 8; ++j) {
        pl = fmaf(acc[j], al8[j], pl);
        pr = fmaf(acc[j], ar8[j], pr);
    }
    pl += __shfl_xor(pl, 1, 64); pl += __shfl_xor(pl, 2, 64); pl += __shfl_xor(pl, 4, 64);
    pr += __shfl_xor(pr, 1, 64); pr += __shfl_xor(pr, 2, 64); pr += __shfl_xor(pr, 4, 64);
    if (cg == 0) {
        const float el = pl;
        // m_i = leaky(e_l + 8): row upper bound; softmax shift-invariance makes it EXACT.
        const float s8 = el + 8.0f;
        const float m = fmaxf(s8, 0.2f * s8);
        el2p[row] = (el - m) * LOG2E;
        cpv[row] = -0.8f * m * LOG2E;
        erp[row] = pr * LOG2E;
    }
#pragma unroll
    for (int j = 0; j < 8; ++j) HbT[(c0 + j) * NN + row] = f2b(acc[j]);
}

// ---------------- Kernel 2: counted-vmcnt pipeline (T3/T4). ------------------------
// grid 512 x 512; block = 32 rows x 4096 cols (16 tiles of 256). 2 blocks/CU.
// Barriers drain ONLY lgkmcnt -> A-prefetch (2 tiles ahead) stays in flight.
// B-fragments issued BEFORE phase1 so their wait leaves A-prefetch outstanding.
__global__ __launch_bounds__(512, 4) void gat_main(
    const int* __restrict__ A, const unsigned short* __restrict__ HbT,
    const float* __restrict__ el2p, const float* __restrict__ cpv,
    const float* __restrict__ erp, float* __restrict__ out, float* __restrict__ dsum)
{
    __shared__ unsigned short plds[2][32 * 264]; // bf16 p, row stride 264
    const int t = threadIdx.x;
    const int l = t & 63;
    const int w = t >> 6;
    const int rowbase = (blockIdx.x >> 1) * 32;
    const int jq16 = (blockIdx.x & 1) * 16;      // first of 16 owned 256-col tiles
    const int l15 = l & 15, lq = l >> 4;

    float el2c[4], cpc[4];
    const int4* Ap[4];
#pragma unroll
    for (int i = 0; i < 4; ++i) {
        const int gr = rowbase + 8 * i + w;
        el2c[i] = el2p[gr];
        cpc[i] = cpv[gr];
        Ap[i] = (const int4*)(A + (long)gr * NN + 4 * l);
    }
    f32x4 acc = {0.f, 0.f, 0.f, 0.f};
    f32x4 accs = {0.f, 0.f, 0.f, 0.f};   // rowsum via ones-B MFMA (nq==0 waves)
    union { unsigned short s[8]; short8v v; } ones;
#pragma unroll
    for (int i = 0; i < 8; ++i) ones.s[i] = 0x3F80; // bf16 1.0
    const int mh = w >> 2, nq = w & 3;
    const bool do_sum = (nq == 0);
    const unsigned short* bbase = HbT + (long)(nq * 16 + l15) * NN + lq * 8;
    const int aoff = (mh * 16 + l15) * 264 + lq * 8;

    int4 A0[4], A1[4];
    float4 E0, E1;
    short8v Bf[8];

    auto loadT = [&](int4* av, float4& e4, int jt) {
        const int jb4 = jt * 64;
#pragma unroll
        for (int i = 0; i < 4; ++i) av[i] = Ap[i][jb4];
        e4 = *(const float4*)(erp + jt * 256 + 4 * l);
    };

    auto issueB = [&](int jt) {
        const unsigned short* bp = bbase + (long)jt * 256;
#pragma unroll
        for (int kc = 0; kc < 8; ++kc) Bf[kc] = *(const short8v*)(bp + kc * 32);
    };

    auto phase1 = [&](const int4* av, const float4 e4, unsigned short* buf) {
        const float e[4] = {e4.x, e4.y, e4.z, e4.w};
#pragma unroll
        for (int i = 0; i < 4; ++i) {
            const int am[4] = {av[i].x, av[i].y, av[i].z, av[i].w};
            unsigned short b[4];
#pragma unroll
            for (int c = 0; c < 4; ++c) {
                const float u = el2c[i] + e[c];
                const float v = fmaf(u, 0.2f, cpc[i]);
                float g = fmaxf(u, v);
                g = am[c] ? g : -1e30f; // non-edge -> exp2 -> 0
                b[c] = f2b(__builtin_amdgcn_exp2f(g));
            }
            const unsigned int lo = (unsigned int)b[0] | ((unsigned int)b[1] << 16);
            const unsigned int hi = (unsigned int)b[2] | ((unsigned int)b[3] << 16);
            *(uint2v*)(buf + (8 * i + w) * 264 + 4 * l) = (uint2v){lo, hi};
        }
    };

    auto mfmaT = [&](const unsigned short* buf) {
#pragma unroll
        for (int kc = 0; kc < 8; ++kc) {
            short8v af = *(const short8v*)(buf + aoff + kc * 32);
            acc = __builtin_amdgcn_mfma_f32_16x16x32_bf16(af, Bf[kc], acc, 0, 0, 0);
            if (do_sum)
                accs = __builtin_amdgcn_mfma_f32_16x16x32_bf16(af, ones.v, accs, 0, 0, 0);
        }
    };

    loadT(A0, E0, jq16);
    loadT(A1, E1, jq16 + 1);
#pragma unroll
    for (int s = 0; s < 8; ++s) {
        const int jt = jq16 + 2 * s;
        issueB(jt);                    // B issued FIRST: its wait leaves A-prefetch alive
        PIN();
        phase1(A0, E0, plds[0]);
        if (s < 7) loadT(A0, E0, jt + 2);
        BAR();                         // lgkmcnt(0) + s_barrier; vmcnt NOT drained
        mfmaT(plds[0]);
        issueB(jt + 1);
        PIN();
        phase1(A1, E1, plds[1]);
        if (s < 7) loadT(A1, E1, jt + 3);
        BAR();
        mfmaT(plds[1]);
    }

    // denominator partials: accs[r] = rowsum(mh*16+lq*4+r), replicated over l15
    if (do_sum && l15 == 0)
#pragma unroll
        for (int r = 0; r < 4; ++r)
            atomicAdd(dsum + rowbase + mh * 16 + lq * 4 + r, accs[r]);
    // numerator partials
#pragma unroll
    for (int r = 0; r < 4; ++r) {
        const int row = mh * 16 + lq * 4 + r; // D layout: col=lane&15, row=(lane>>4)*4+r
        atomicAdd(out + (long)(rowbase + row) * HDIM + nq * 16 + l15, acc[r]);
    }
}

// ---------------- Kernel 3: out *= 1/dsum[row] ------------------------------------
__global__ __launch_bounds__(256) void gat_norm(float* __restrict__ out,
                                                const float* __restrict__ dsum)
{
    const int i4 = blockIdx.x * 256 + threadIdx.x; // float4 index; 16 per row
    float4 v = ((float4*)out)[i4];
    const float ri = 1.0f / dsum[i4 >> 4];
    v.x *= ri; v.y *= ri; v.z *= ri; v.w *= ri;
    ((float4*)out)[i4] = v;
}

extern "C" void kernel_launch(void* const* d_in, const int* in_sizes, int n_in,
                              void* d_out, int out_size, void* d_ws, size_t ws_size,
                              hipStream_t stream) {
    const float *X = nullptr, *W = nullptr, *al = nullptr, *ar = nullptr;
    const int* A = nullptr;
    for (int i = 0; i < n_in; ++i) {
        const long s = in_sizes[i];
        if (s == (long)NN * NN) A = (const int*)d_in[i];
        else if (s == (long)NN * KDIM) X = (const float*)d_in[i];
        else if (s == (long)KDIM * HDIM) W = (const float*)d_in[i];
        else if (s == HDIM) { if (!al) al = (const float*)d_in[i]; else ar = (const float*)d_in[i]; }
    }
    float* out = (float*)d_out;
    // ws: HbT (1MB) + el2p/cpv/erp/dsum (4 x 32KB)
    unsigned short* HbT = (unsigned short*)d_ws;
    float* el2p = (float*)((char*)d_ws + (long)NN * HDIM * 2);
    float* cpv = el2p + NN;
    float* erp = cpv + NN;
    float* dsum = erp + NN;
    hipMemsetAsync(d_out, 0, (long)NN * HDIM * sizeof(float), stream);
    hipMemsetAsync(dsum, 0, NN * sizeof(float), stream);
    hipLaunchKernelGGL(gat_prep, dim3(256), dim3(256), 0, stream, X, W, al, ar, HbT, el2p, cpv, erp);
    hipLaunchKernelGGL(gat_main, dim3(512), dim3(512), 0, stream, A, HbT, el2p, cpv, erp, out, dsum);
    hipLaunchKernelGGL(gat_norm, dim3(512), dim3(256), 0, stream, out, dsum);
}

// Round 13
// 102.613 us; speedup vs baseline: 1.5868x; 1.0063x over previous
//
#include <hip/hip_runtime.h>

typedef __attribute__((ext_vector_type(8))) short short8v;
typedef __attribute__((ext_vector_type(4))) float f32x4;
typedef __attribute__((ext_vector_type(2))) unsigned int uint2v;

#define NN 8192
#define HDIM 64
#define KDIM 128
#define LOG2E 1.44269504088896340736f

#define PIN() asm volatile("" ::: "memory")
// Barrier WITHOUT vmcnt drain: LDS hazards need only lgkmcnt(0).
// (ds_writes complete before barrier; ds_reads of the outgoing buffer are also
//  lgkm-drained, so the next phase's writes to the other buffer are WAR-safe.)
#define BAR() asm volatile("s_waitcnt lgkmcnt(0)\n\ts_barrier" ::: "memory")

__device__ __forceinline__ unsigned short f2b(float f) {
    unsigned int u = __float_as_uint(f);
    return (unsigned short)((u + 0x7fffu + ((u >> 16) & 1u)) >> 16);
}

// ---------------- Kernel 1 (verified R3-R9): H = X@W, softmax row constants, HbT bf16 ----
__global__ __launch_bounds__(256) void gat_prep(
    const float* __restrict__ X, const float* __restrict__ W,
    const float* __restrict__ al, const float* __restrict__ ar,
    unsigned short* __restrict__ HbT, float* __restrict__ el2p,
    float* __restrict__ cpv, float* __restrict__ erp)
{
    __shared__ float Wl[KDIM * HDIM];
    const int t = threadIdx.x;
    {
        const float4* Wv = (const float4*)W;
        float4* Wlv = (float4*)Wl;
#pragma unroll
        for (int s = 0; s < 8; ++s) Wlv[t + s * 256] = Wv[t + s * 256];
    }
    __syncthreads();
    const int row = blockIdx.x * 32 + (t >> 3);
    const int cg = t & 7;
    const int c0 = cg * 8;
    float al8[8], ar8[8];
#pragma unroll
    for (int j = 0; j < 8; ++j) { al8[j] = al[c0 + j]; ar8[j] = ar[c0 + j]; }
    float acc[8];
#pragma unroll
    for (int j = 0; j < 8; ++j) acc[j] = 0.f;
    const float4* Xv = (const float4*)(X + row * KDIM);
    for (int k4 = 0; k4 < 32; ++k4) {
        float4 x4 = Xv[k4];
        float xs[4] = {x4.x, x4.y, x4.z, x4.w};
#pragma unroll
        for (int kk = 0; kk < 4; ++kk) {
            const int k = k4 * 4 + kk;
            const float x = xs[kk];
            const float4 w0 = *(const float4*)&Wl[k * HDIM + c0];
            const float4 w1 = *(const float4*)&Wl[k * HDIM + c0 + 4];
            acc[0] = fmaf(x, w0.x, acc[0]); acc[1] = fmaf(x, w0.y, acc[1]);
            acc[2] = fmaf(x, w0.z, acc[2]); acc[3] = fmaf(x, w0.w, acc[3]);
            acc[4] = fmaf(x, w1.x, acc[4]); acc[5] = fmaf(x, w1.y, acc[5]);
            acc[6] = fmaf(x, w1.z, acc[6]); acc[7] = fmaf(x, w1.w, acc[7]);
        }
    }
    float pl = 0.f, pr = 0.f;
#pragma unroll
    for (int j = 0; j < 8; ++j) {
        pl = fmaf(acc[j], al8[j], pl);
        pr = fmaf(acc[j], ar8[j], pr);
    }
    pl += __shfl_xor(pl, 1, 64); pl += __shfl_xor(pl, 2, 64); pl += __shfl_xor(pl, 4, 64);
    pr += __shfl_xor(pr, 1, 64); pr += __shfl_xor(pr, 2, 64); pr += __shfl_xor(pr, 4, 64);
    if (cg == 0) {
        const float el = pl;
        // m_i = leaky(e_l + 8): row upper bound; softmax shift-invariance makes it EXACT.
        const float s8 = el + 8.0f;
        const float m = fmaxf(s8, 0.2f * s8);
        el2p[row] = (el - m) * LOG2E;
        cpv[row] = -0.8f * m * LOG2E;
        erp[row] = pr * LOG2E;
    }
#pragma unroll
    for (int j = 0; j < 8; ++j) HbT[(c0 + j) * NN + row] = f2b(acc[j]);
}

// ---------------- Kernel 2: counted-vmcnt pipeline (T3/T4). ------------------------
// grid 512 x 512; block = 32 rows x 4096 cols (16 tiles of 256). 2 blocks/CU.
// Barriers drain ONLY lgkmcnt -> A-prefetch (2 tiles ahead) stays in flight.
// B-fragments issued BEFORE phase1 so their wait leaves A-prefetch outstanding.
__global__ __launch_bounds__(512, 4) void gat_main(
    const int* __restrict__ A, const unsigned short* __restrict__ HbT,
    const float* __restrict__ el2p, const float* __restrict__ cpv,
    const float* __restrict__ erp, float* __restrict__ out, float* __restrict__ dsum)
{
    __shared__ unsigned short plds[2][32 * 264]; // bf16 p, row stride 264
    const int t = threadIdx.x;
    const int l = t & 63;
    const int w = t >> 6;
    const int rowbase = (blockIdx.x >> 1) * 32;
    const int jq16 = (blockIdx.x & 1) * 16;      // first of 16 owned 256-col tiles
    const int l15 = l & 15, lq = l >> 4;

    float el2c[4], cpc[4];
    const int4* Ap[4];
#pragma unroll
    for (int i = 0; i < 4; ++i) {
        const int gr = rowbase + 8 * i + w;
        el2c[i] = el2p[gr];
        cpc[i] = cpv[gr];
        Ap[i] = (const int4*)(A + (long)gr * NN + 4 * l);
    }
    f32x4 acc = {0.f, 0.f, 0.f, 0.f};
    f32x4 accs = {0.f, 0.f, 0.f, 0.f};   // rowsum via ones-B MFMA (nq==0 waves)
    union { unsigned short s[8]; short8v v; } ones;
#pragma unroll
    for (int i = 0; i < 8; ++i) ones.s[i] = 0x3F80; // bf16 1.0
    const int mh = w >> 2, nq = w & 3;
    const bool do_sum = (nq == 0);
    const unsigned short* bbase = HbT + (long)(nq * 16 + l15) * NN + lq * 8;
    const int aoff = (mh * 16 + l15) * 264 + lq * 8;

    int4 A0[4], A1[4];
    float4 E0, E1;
    short8v Bf[8];

    auto loadT = [&](int4* av, float4& e4, int jt) {
        const int jb4 = jt * 64;
#pragma unroll
        for (int i = 0; i < 4; ++i) av[i] = Ap[i][jb4];
        e4 = *(const float4*)(erp + jt * 256 + 4 * l);
    };

    auto issueB = [&](int jt) {
        const unsigned short* bp = bbase + (long)jt * 256;
#pragma unroll
        for (int kc = 0; kc < 8; ++kc) Bf[kc] = *(const short8v*)(bp + kc * 32);
    };

    auto phase1 = [&](const int4* av, const float4 e4, unsigned short* buf) {
        const float e[4] = {e4.x, e4.y, e4.z, e4.w};
#pragma unroll
        for (int i = 0; i < 4; ++i) {
            const int am[4] = {av[i].x, av[i].y, av[i].z, av[i].w};
            unsigned short b[4];
#pragma unroll
            for (int c = 0; c < 4; ++c) {
                const float u = el2c[i] + e[c];
                const float v = fmaf(u, 0.2f, cpc[i]);
                float g = fmaxf(u, v);
                g = am[c] ? g : -1e30f; // non-edge -> exp2 -> 0
                b[c] = f2b(__builtin_amdgcn_exp2f(g));
            }
            const unsigned int lo = (unsigned int)b[0] | ((unsigned int)b[1] << 16);
            const unsigned int hi = (unsigned int)b[2] | ((unsigned int)b[3] << 16);
            *(uint2v*)(buf + (8 * i + w) * 264 + 4 * l) = (uint2v){lo, hi};
        }
    };

    auto mfmaT = [&](const unsigned short* buf) {
#pragma unroll
        for (int kc = 0; kc < 8; ++kc) {
            short8v af = *(const short8v*)(buf + aoff + kc * 32);
            acc = __builtin_amdgcn_mfma_f32_16x16x32_bf16(af, Bf[kc], acc, 0, 0, 0);
            if (do_sum)
                accs = __builtin_amdgcn_mfma_f32_16x16x32_bf16(af, ones.v, accs, 0, 0, 0);
        }
    };

    loadT(A0, E0, jq16);
    loadT(A1, E1, jq16 + 1);
#pragma unroll
    for (int s = 0; s < 8; ++s) {
        const int jt = jq16 + 2 * s;
        issueB(jt);                    // B issued FIRST: its wait leaves A-prefetch alive
        PIN();
        phase1(A0, E0, plds[0]);
        if (s < 7) loadT(A0, E0, jt + 2);
        BAR();                         // lgkmcnt(0) + s_barrier; vmcnt NOT drained
        mfmaT(plds[0]);
        issueB(jt + 1);
        PIN();
        phase1(A1, E1, plds[1]);
        if (s < 7) loadT(A1, E1, jt + 3);
        BAR();
        mfmaT(plds[1]);
    }

    // denominator partials: accs[r] = rowsum(mh*16+lq*4+r), replicated over l15
    if (do_sum && l15 == 0)
#pragma unroll
        for (int r = 0; r < 4; ++r)
            atomicAdd(dsum + rowbase + mh * 16 + lq * 4 + r, accs[r]);
    // numerator partials
#pragma unroll
    for (int r = 0; r < 4; ++r) {
        const int row = mh * 16 + lq * 4 + r; // D layout: col=lane&15, row=(lane>>4)*4+r
        atomicAdd(out + (long)(rowbase + row) * HDIM + nq * 16 + l15, acc[r]);
    }
}

// ---------------- Kernel 3: out *= 1/dsum[row] ------------------------------------
__global__ __launch_bounds__(256) void gat_norm(float* __restrict__ out,
                                                const float* __restrict__ dsum)
{
    const int i4 = blockIdx.x * 256 + threadIdx.x; // float4 index; 16 per row
    float4 v = ((float4*)out)[i4];
    const float ri = 1.0f / dsum[i4 >> 4];
    v.x *= ri; v.y *= ri; v.z *= ri; v.w *= ri;
    ((float4*)out)[i4] = v;
}

extern "C" void kernel_launch(void* const* d_in, const int* in_sizes, int n_in,
                              void* d_out, int out_size, void* d_ws, size_t ws_size,
                              hipStream_t stream) {
    const float *X = nullptr, *W = nullptr, *al = nullptr, *ar = nullptr;
    const int* A = nullptr;
    for (int i = 0; i < n_in; ++i) {
        const long s = in_sizes[i];
        if (s == (long)NN * NN) A = (const int*)d_in[i];
        else if (s == (long)NN * KDIM) X = (const float*)d_in[i];
        else if (s == (long)KDIM * HDIM) W = (const float*)d_in[i];
        else if (s == HDIM) { if (!al) al = (const float*)d_in[i]; else ar = (const float*)d_in[i]; }
    }
    float* out = (float*)d_out;
    // ws: HbT (1MB) + el2p/cpv/erp/dsum (4 x 32KB)
    unsigned short* HbT = (unsigned short*)d_ws;
    float* el2p = (float*)((char*)d_ws + (long)NN * HDIM * 2);
    float* cpv = el2p + NN;
    float* erp = cpv + NN;
    float* dsum = erp + NN;
    hipMemsetAsync(d_out, 0, (long)NN * HDIM * sizeof(float), stream);
    hipMemsetAsync(dsum, 0, NN * sizeof(float), stream);
    hipLaunchKernelGGL(gat_prep, dim3(256), dim3(256), 0, stream, X, W, al, ar, HbT, el2p, cpv, erp);
    hipLaunchKernelGGL(gat_main, dim3(512), dim3(512), 0, stream, A, HbT, el2p, cpv, erp, out, dsum);
    hipLaunchKernelGGL(gat_norm, dim3(512), dim3(256), 0, stream, out, dsum);
}

// Round 14
// 95.491 us; speedup vs baseline: 1.7051x; 1.0746x over previous
//
#include <hip/hip_runtime.h>

typedef __attribute__((ext_vector_type(8))) short short8v;
typedef __attribute__((ext_vector_type(4))) float f32x4;
typedef __attribute__((ext_vector_type(2))) unsigned int uint2v;

#define NN 8192
#define HDIM 64
#define KDIM 128
#define LOG2E 1.44269504088896340736f

#define PIN() asm volatile("" ::: "memory")
// Barrier WITHOUT vmcnt drain: LDS hazards need only lgkmcnt(0).
#define BAR() asm volatile("s_waitcnt lgkmcnt(0)\n\ts_barrier" ::: "memory")

__device__ __forceinline__ unsigned short f2b(float f) {
    unsigned int u = __float_as_uint(f);
    return (unsigned short)((u + 0x7fffu + ((u >> 16) & 1u)) >> 16);
}

// ---------------- Kernel 1: H = X@W, softmax row constants, HbT bf16. ----------------
// R14 delta (a): fused zero-fill of out/dsum replaces the two hipMemsetAsync dispatches.
__global__ __launch_bounds__(256) void gat_prep(
    const float* __restrict__ X, const float* __restrict__ W,
    const float* __restrict__ al, const float* __restrict__ ar,
    unsigned short* __restrict__ HbT, float* __restrict__ el2p,
    float* __restrict__ cpv, float* __restrict__ erp,
    float* __restrict__ outz, float* __restrict__ dsumz)
{
    __shared__ float Wl[KDIM * HDIM];
    const int t = threadIdx.x;
    {   // zero-fill accumulation buffers (coverage: 131072 float4 = 2MB out; 8192 dsum)
        const int gt = blockIdx.x * 256 + t;       // 0..65535
        const float4 z = {0.f, 0.f, 0.f, 0.f};
        float4* ov = (float4*)outz;
        ov[gt] = z;
        ov[gt + 65536] = z;
        if (blockIdx.x < 32) dsumz[gt] = 0.f;
    }
    {
        const float4* Wv = (const float4*)W;
        float4* Wlv = (float4*)Wl;
#pragma unroll
        for (int s = 0; s < 8; ++s) Wlv[t + s * 256] = Wv[t + s * 256];
    }
    __syncthreads();
    const int row = blockIdx.x * 32 + (t >> 3);
    const int cg = t & 7;
    const int c0 = cg * 8;
    float al8[8], ar8[8];
#pragma unroll
    for (int j = 0; j < 8; ++j) { al8[j] = al[c0 + j]; ar8[j] = ar[c0 + j]; }
    float acc[8];
#pragma unroll
    for (int j = 0; j < 8; ++j) acc[j] = 0.f;
    const float4* Xv = (const float4*)(X + row * KDIM);
    for (int k4 = 0; k4 < 32; ++k4) {
        float4 x4 = Xv[k4];
        float xs[4] = {x4.x, x4.y, x4.z, x4.w};
#pragma unroll
        for (int kk = 0; kk < 4; ++kk) {
            const int k = k4 * 4 + kk;
            const float x = xs[kk];
            const float4 w0 = *(const float4*)&Wl[k * HDIM + c0];
            const float4 w1 = *(const float4*)&Wl[k * HDIM + c0 + 4];
            acc[0] = fmaf(x, w0.x, acc[0]); acc[1] = fmaf(x, w0.y, acc[1]);
            acc[2] = fmaf(x, w0.z, acc[2]); acc[3] = fmaf(x, w0.w, acc[3]);
            acc[4] = fmaf(x, w1.x, acc[4]); acc[5] = fmaf(x, w1.y, acc[5]);
            acc[6] = fmaf(x, w1.z, acc[6]); acc[7] = fmaf(x, w1.w, acc[7]);
        }
    }
    float pl = 0.f, pr = 0.f;
#pragma unroll
    for (int j = 0; j < 8; ++j) {
        pl = fmaf(acc[j], al8[j], pl);
        pr = fmaf(acc[j], ar8[j], pr);
    }
    pl += __shfl_xor(pl, 1, 64); pl += __shfl_xor(pl, 2, 64); pl += __shfl_xor(pl, 4, 64);
    pr += __shfl_xor(pr, 1, 64); pr += __shfl_xor(pr, 2, 64); pr += __shfl_xor(pr, 4, 64);
    if (cg == 0) {
        const float el = pl;
        // m_i = leaky(e_l + 8): row upper bound; softmax shift-invariance makes it EXACT.
        const float s8 = el + 8.0f;
        const float m = fmaxf(s8, 0.2f * s8);
        el2p[row] = (el - m) * LOG2E;
        cpv[row] = -0.8f * m * LOG2E;
        erp[row] = pr * LOG2E;
    }
#pragma unroll
    for (int j = 0; j < 8; ++j) HbT[(c0 + j) * NN + row] = f2b(acc[j]);
}

// ---------------- Kernel 2: counted-vmcnt pipeline (R9/R13-verified structure). -----
// grid 512 x 512; block = 32 rows x 4096 cols (16 tiles of 256). 2 blocks/CU.
// R14 delta (b): s_setprio(1)/(0) around the MFMA cluster (T5). phase1 FROZEN (f2b).
__global__ __launch_bounds__(512, 4) void gat_main(
    const int* __restrict__ A, const unsigned short* __restrict__ HbT,
    const float* __restrict__ el2p, const float* __restrict__ cpv,
    const float* __restrict__ erp, float* __restrict__ out, float* __restrict__ dsum)
{
    __shared__ unsigned short plds[2][32 * 264]; // bf16 p, row stride 264
    const int t = threadIdx.x;
    const int l = t & 63;
    const int w = t >> 6;
    const int rowbase = (blockIdx.x >> 1) * 32;
    const int jq16 = (blockIdx.x & 1) * 16;      // first of 16 owned 256-col tiles
    const int l15 = l & 15, lq = l >> 4;

    float el2c[4], cpc[4];
    const int4* Ap[4];
#pragma unroll
    for (int i = 0; i < 4; ++i) {
        const int gr = rowbase + 8 * i + w;
        el2c[i] = el2p[gr];
        cpc[i] = cpv[gr];
        Ap[i] = (const int4*)(A + (long)gr * NN + 4 * l);
    }
    f32x4 acc = {0.f, 0.f, 0.f, 0.f};
    f32x4 accs = {0.f, 0.f, 0.f, 0.f};   // rowsum via ones-B MFMA (nq==0 waves)
    union { unsigned short s[8]; short8v v; } ones;
#pragma unroll
    for (int i = 0; i < 8; ++i) ones.s[i] = 0x3F80; // bf16 1.0
    const int mh = w >> 2, nq = w & 3;
    const bool do_sum = (nq == 0);
    const unsigned short* bbase = HbT + (long)(nq * 16 + l15) * NN + lq * 8;
    const int aoff = (mh * 16 + l15) * 264 + lq * 8;

    int4 A0[4], A1[4];
    float4 E0, E1;
    short8v Bf[8];

    auto loadT = [&](int4* av, float4& e4, int jt) {
        const int jb4 = jt * 64;
#pragma unroll
        for (int i = 0; i < 4; ++i) av[i] = Ap[i][jb4];
        e4 = *(const float4*)(erp + jt * 256 + 4 * l);
    };

    auto issueB = [&](int jt) {
        const unsigned short* bp = bbase + (long)jt * 256;
#pragma unroll
        for (int kc = 0; kc < 8; ++kc) Bf[kc] = *(const short8v*)(bp + kc * 32);
    };

    auto phase1 = [&](const int4* av, const float4 e4, unsigned short* buf) {
        const float e[4] = {e4.x, e4.y, e4.z, e4.w};
#pragma unroll
        for (int i = 0; i < 4; ++i) {
            const int am[4] = {av[i].x, av[i].y, av[i].z, av[i].w};
            unsigned short b[4];
#pragma unroll
            for (int c = 0; c < 4; ++c) {
                const float u = el2c[i] + e[c];
                const float v = fmaf(u, 0.2f, cpc[i]);
                float g = fmaxf(u, v);
                g = am[c] ? g : -1e30f; // non-edge -> exp2 -> 0
                b[c] = f2b(__builtin_amdgcn_exp2f(g));
            }
            const unsigned int lo = (unsigned int)b[0] | ((unsigned int)b[1] << 16);
            const unsigned int hi = (unsigned int)b[2] | ((unsigned int)b[3] << 16);
            *(uint2v*)(buf + (8 * i + w) * 264 + 4 * l) = (uint2v){lo, hi};
        }
    };

    auto mfmaT = [&](const unsigned short* buf) {
        __builtin_amdgcn_s_setprio(1);
#pragma unroll
        for (int kc = 0; kc < 8; ++kc) {
            short8v af = *(const short8v*)(buf + aoff + kc * 32);
            acc = __builtin_amdgcn_mfma_f32_16x16x32_bf16(af, Bf[kc], acc, 0, 0, 0);
            if (do_sum)
                accs = __builtin_amdgcn_mfma_f32_16x16x32_bf16(af, ones.v, accs, 0, 0, 0);
        }
        __builtin_amdgcn_s_setprio(0);
    };

    loadT(A0, E0, jq16);
    loadT(A1, E1, jq16 + 1);
#pragma unroll
    for (int s = 0; s < 8; ++s) {
        const int jt = jq16 + 2 * s;
        issueB(jt);                    // B issued FIRST: its wait leaves A-prefetch alive
        PIN();
        phase1(A0, E0, plds[0]);
        if (s < 7) loadT(A0, E0, jt + 2);
        BAR();                         // lgkmcnt(0) + s_barrier; vmcnt NOT drained
        mfmaT(plds[0]);
        issueB(jt + 1);
        PIN();
        phase1(A1, E1, plds[1]);
        if (s < 7) loadT(A1, E1, jt + 3);
        BAR();
        mfmaT(plds[1]);
    }

    // denominator partials: accs[r] = rowsum(mh*16+lq*4+r), replicated over l15
    if (do_sum && l15 == 0)
#pragma unroll
        for (int r = 0; r < 4; ++r)
            atomicAdd(dsum + rowbase + mh * 16 + lq * 4 + r, accs[r]);
    // numerator partials
#pragma unroll
    for (int r = 0; r < 4; ++r) {
        const int row = mh * 16 + lq * 4 + r; // D layout: col=lane&15, row=(lane>>4)*4+r
        atomicAdd(out + (long)(rowbase + row) * HDIM + nq * 16 + l15, acc[r]);
    }
}

// ---------------- Kernel 3: out *= 1/dsum[row] ------------------------------------
__global__ __launch_bounds__(256) void gat_norm(float* __restrict__ out,
                                                const float* __restrict__ dsum)
{
    const int i4 = blockIdx.x * 256 + threadIdx.x; // float4 index; 16 per row
    float4 v = ((float4*)out)[i4];
    const float ri = 1.0f / dsum[i4 >> 4];
    v.x *= ri; v.y *= ri; v.z *= ri; v.w *= ri;
    ((float4*)out)[i4] = v;
}

extern "C" void kernel_launch(void* const* d_in, const int* in_sizes, int n_in,
                              void* d_out, int out_size, void* d_ws, size_t ws_size,
                              hipStream_t stream) {
    const float *X = nullptr, *W = nullptr, *al = nullptr, *ar = nullptr;
    const int* A = nullptr;
    for (int i = 0; i < n_in; ++i) {
        const long s = in_sizes[i];
        if (s == (long)NN * NN) A = (const int*)d_in[i];
        else if (s == (long)NN * KDIM) X = (const float*)d_in[i];
        else if (s == (long)KDIM * HDIM) W = (const float*)d_in[i];
        else if (s == HDIM) { if (!al) al = (const float*)d_in[i]; else ar = (const float*)d_in[i]; }
    }
    float* out = (float*)d_out;
    // ws: HbT (1MB) + el2p/cpv/erp/dsum (4 x 32KB)
    unsigned short* HbT = (unsigned short*)d_ws;
    float* el2p = (float*)((char*)d_ws + (long)NN * HDIM * 2);
    float* cpv = el2p + NN;
    float* erp = cpv + NN;
    float* dsum = erp + NN;
    hipLaunchKernelGGL(gat_prep, dim3(256), dim3(256), 0, stream, X, W, al, ar, HbT, el2p, cpv, erp, out, dsum);
    hipLaunchKernelGGL(gat_main, dim3(512), dim3(512), 0, stream, A, HbT, el2p, cpv, erp, out, dsum);
    hipLaunchKernelGGL(gat_norm, dim3(512), dim3(256), 0, stream, out, dsum);
}

// Round 15
// 91.921 us; speedup vs baseline: 1.7713x; 1.0388x over previous
//
#include <hip/hip_runtime.h>

typedef __attribute__((ext_vector_type(8))) short short8v;
typedef __attribute__((ext_vector_type(4))) float f32x4;
typedef __attribute__((ext_vector_type(2))) unsigned int uint2v;

#define NN 8192
#define HDIM 64
#define KDIM 128
#define LOG2E 1.44269504088896340736f

#define PIN() asm volatile("" ::: "memory")
// Barrier WITHOUT vmcnt drain: LDS hazards need only lgkmcnt(0).
#define BAR() asm volatile("s_waitcnt lgkmcnt(0)\n\ts_barrier" ::: "memory")

__device__ __forceinline__ unsigned short f2b(float f) {
    unsigned int u = __float_as_uint(f);
    return (unsigned short)((u + 0x7fffu + ((u >> 16) & 1u)) >> 16);
}

// ---------------- Kernel 1 (R14-verified): H = X@W, consts, HbT bf16, fused zero-fill ----
__global__ __launch_bounds__(256) void gat_prep(
    const float* __restrict__ X, const float* __restrict__ W,
    const float* __restrict__ al, const float* __restrict__ ar,
    unsigned short* __restrict__ HbT, float* __restrict__ el2p,
    float* __restrict__ cpv, float* __restrict__ erp,
    float* __restrict__ outz, float* __restrict__ dsumz)
{
    __shared__ float Wl[KDIM * HDIM];
    const int t = threadIdx.x;
    {   // zero-fill accumulation buffers (131072 float4 = 2MB out; 8192 dsum)
        const int gt = blockIdx.x * 256 + t;
        const float4 z = {0.f, 0.f, 0.f, 0.f};
        float4* ov = (float4*)outz;
        ov[gt] = z;
        ov[gt + 65536] = z;
        if (blockIdx.x < 32) dsumz[gt] = 0.f;
    }
    {
        const float4* Wv = (const float4*)W;
        float4* Wlv = (float4*)Wl;
#pragma unroll
        for (int s = 0; s < 8; ++s) Wlv[t + s * 256] = Wv[t + s * 256];
    }
    __syncthreads();
    const int row = blockIdx.x * 32 + (t >> 3);
    const int cg = t & 7;
    const int c0 = cg * 8;
    float al8[8], ar8[8];
#pragma unroll
    for (int j = 0; j < 8; ++j) { al8[j] = al[c0 + j]; ar8[j] = ar[c0 + j]; }
    float acc[8];
#pragma unroll
    for (int j = 0; j < 8; ++j) acc[j] = 0.f;
    const float4* Xv = (const float4*)(X + row * KDIM);
    for (int k4 = 0; k4 < 32; ++k4) {
        float4 x4 = Xv[k4];
        float xs[4] = {x4.x, x4.y, x4.z, x4.w};
#pragma unroll
        for (int kk = 0; kk < 4; ++kk) {
            const int k = k4 * 4 + kk;
            const float x = xs[kk];
            const float4 w0 = *(const float4*)&Wl[k * HDIM + c0];
            const float4 w1 = *(const float4*)&Wl[k * HDIM + c0 + 4];
            acc[0] = fmaf(x, w0.x, acc[0]); acc[1] = fmaf(x, w0.y, acc[1]);
            acc[2] = fmaf(x, w0.z, acc[2]); acc[3] = fmaf(x, w0.w, acc[3]);
            acc[4] = fmaf(x, w1.x, acc[4]); acc[5] = fmaf(x, w1.y, acc[5]);
            acc[6] = fmaf(x, w1.z, acc[6]); acc[7] = fmaf(x, w1.w, acc[7]);
        }
    }
    float pl = 0.f, pr = 0.f;
#pragma unroll
    for (int j = 0; j < 8; ++j) {
        pl = fmaf(acc[j], al8[j], pl);
        pr = fmaf(acc[j], ar8[j], pr);
    }
    pl += __shfl_xor(pl, 1, 64); pl += __shfl_xor(pl, 2, 64); pl += __shfl_xor(pl, 4, 64);
    pr += __shfl_xor(pr, 1, 64); pr += __shfl_xor(pr, 2, 64); pr += __shfl_xor(pr, 4, 64);
    if (cg == 0) {
        const float el = pl;
        // m_i = leaky(e_l + 8): row upper bound; softmax shift-invariance makes it EXACT.
        const float s8 = el + 8.0f;
        const float m = fmaxf(s8, 0.2f * s8);
        el2p[row] = (el - m) * LOG2E;
        cpv[row] = -0.8f * m * LOG2E;
        erp[row] = pr * LOG2E;
    }
#pragma unroll
    for (int j = 0; j < 8; ++j) HbT[(c0 + j) * NN + row] = f2b(acc[j]);
}

// ---------------- Kernel 2: counted-vmcnt pipeline; 256-thr blocks, 4 groups/CU -----
// grid 1024 x 256; block = 16 rows x 4096 cols (16 tiles of 256). 4 blocks/CU.
// Mechanical reshape of the R9/R13/R14-verified kernel: mh->0, nq->w, rows {4i+w}.
__global__ __launch_bounds__(256, 4) void gat_main(
    const int* __restrict__ A, const unsigned short* __restrict__ HbT,
    const float* __restrict__ el2p, const float* __restrict__ cpv,
    const float* __restrict__ erp, float* __restrict__ out, float* __restrict__ dsum)
{
    __shared__ unsigned short plds[2][16 * 264]; // bf16 p, row stride 264
    const int t = threadIdx.x;
    const int l = t & 63;
    const int w = t >> 6;                        // 4 waves
    const int rowbase = (blockIdx.x >> 1) * 16;
    const int jq16 = (blockIdx.x & 1) * 16;      // first of 16 owned 256-col tiles
    const int l15 = l & 15, lq = l >> 4;

    float el2c[4], cpc[4];
    const int4* Ap[4];
#pragma unroll
    for (int i = 0; i < 4; ++i) {
        const int gr = rowbase + 4 * i + w;
        el2c[i] = el2p[gr];
        cpc[i] = cpv[gr];
        Ap[i] = (const int4*)(A + (long)gr * NN + 4 * l);
    }
    f32x4 acc = {0.f, 0.f, 0.f, 0.f};
    f32x4 accs = {0.f, 0.f, 0.f, 0.f};   // rowsum via ones-B MFMA (wave 0)
    union { unsigned short s[8]; short8v v; } ones;
#pragma unroll
    for (int i = 0; i < 8; ++i) ones.s[i] = 0x3F80; // bf16 1.0
    const bool do_sum = (w == 0);
    const unsigned short* bbase = HbT + (long)(w * 16 + l15) * NN + lq * 8;
    const int aoff = l15 * 264 + lq * 8;

    int4 A0[4], A1[4];
    float4 E0, E1;
    short8v Bf[8];

    auto loadT = [&](int4* av, float4& e4, int jt) {
        const int jb4 = jt * 64;
#pragma unroll
        for (int i = 0; i < 4; ++i) av[i] = Ap[i][jb4];
        e4 = *(const float4*)(erp + jt * 256 + 4 * l);
    };

    auto issueB = [&](int jt) {
        const unsigned short* bp = bbase + (long)jt * 256;
#pragma unroll
        for (int kc = 0; kc < 8; ++kc) Bf[kc] = *(const short8v*)(bp + kc * 32);
    };

    auto phase1 = [&](const int4* av, const float4 e4, unsigned short* buf) {
        const float e[4] = {e4.x, e4.y, e4.z, e4.w};
#pragma unroll
        for (int i = 0; i < 4; ++i) {
            const int am[4] = {av[i].x, av[i].y, av[i].z, av[i].w};
            unsigned short b[4];
#pragma unroll
            for (int c = 0; c < 4; ++c) {
                const float u = el2c[i] + e[c];
                const float v = fmaf(u, 0.2f, cpc[i]);
                float g = fmaxf(u, v);
                g = am[c] ? g : -1e30f; // non-edge -> exp2 -> 0
                b[c] = f2b(__builtin_amdgcn_exp2f(g));
            }
            const unsigned int lo = (unsigned int)b[0] | ((unsigned int)b[1] << 16);
            const unsigned int hi = (unsigned int)b[2] | ((unsigned int)b[3] << 16);
            *(uint2v*)(buf + (4 * i + w) * 264 + 4 * l) = (uint2v){lo, hi};
        }
    };

    auto mfmaT = [&](const unsigned short* buf) {
        __builtin_amdgcn_s_setprio(1);
#pragma unroll
        for (int kc = 0; kc < 8; ++kc) {
            short8v af = *(const short8v*)(buf + aoff + kc * 32);
            acc = __builtin_amdgcn_mfma_f32_16x16x32_bf16(af, Bf[kc], acc, 0, 0, 0);
            if (do_sum)
                accs = __builtin_amdgcn_mfma_f32_16x16x32_bf16(af, ones.v, accs, 0, 0, 0);
        }
        __builtin_amdgcn_s_setprio(0);
    };

    loadT(A0, E0, jq16);
    loadT(A1, E1, jq16 + 1);
#pragma unroll
    for (int s = 0; s < 8; ++s) {
        const int jt = jq16 + 2 * s;
        issueB(jt);                    // B issued FIRST: its wait leaves A-prefetch alive
        PIN();
        phase1(A0, E0, plds[0]);
        if (s < 7) loadT(A0, E0, jt + 2);
        BAR();                         // lgkmcnt(0) + s_barrier; vmcnt NOT drained
        mfmaT(plds[0]);
        issueB(jt + 1);
        PIN();
        phase1(A1, E1, plds[1]);
        if (s < 7) loadT(A1, E1, jt + 3);
        BAR();
        mfmaT(plds[1]);
    }

    // denominator partials: accs[r] = rowsum(lq*4+r), replicated over l15
    if (do_sum && l15 == 0)
#pragma unroll
        for (int r = 0; r < 4; ++r)
            atomicAdd(dsum + rowbase + lq * 4 + r, accs[r]);
    // numerator partials
#pragma unroll
    for (int r = 0; r < 4; ++r) {
        const int row = lq * 4 + r;   // D layout: col=lane&15, row=(lane>>4)*4+r
        atomicAdd(out + (long)(rowbase + row) * HDIM + w * 16 + l15, acc[r]);
    }
}

// ---------------- Kernel 3: out *= 1/dsum[row] ------------------------------------
__global__ __launch_bounds__(256) void gat_norm(float* __restrict__ out,
                                                const float* __restrict__ dsum)
{
    const int i4 = blockIdx.x * 256 + threadIdx.x; // float4 index; 16 per row
    float4 v = ((float4*)out)[i4];
    const float ri = 1.0f / dsum[i4 >> 4];
    v.x *= ri; v.y *= ri; v.z *= ri; v.w *= ri;
    ((float4*)out)[i4] = v;
}

extern "C" void kernel_launch(void* const* d_in, const int* in_sizes, int n_in,
                              void* d_out, int out_size, void* d_ws, size_t ws_size,
                              hipStream_t stream) {
    const float *X = nullptr, *W = nullptr, *al = nullptr, *ar = nullptr;
    const int* A = nullptr;
    for (int i = 0; i < n_in; ++i) {
        const long s = in_sizes[i];
        if (s == (long)NN * NN) A = (const int*)d_in[i];
        else if (s == (long)NN * KDIM) X = (const float*)d_in[i];
        else if (s == (long)KDIM * HDIM) W = (const float*)d_in[i];
        else if (s == HDIM) { if (!al) al = (const float*)d_in[i]; else ar = (const float*)d_in[i]; }
    }
    float* out = (float*)d_out;
    // ws: HbT (1MB) + el2p/cpv/erp/dsum (4 x 32KB)
    unsigned short* HbT = (unsigned short*)d_ws;
    float* el2p = (float*)((char*)d_ws + (long)NN * HDIM * 2);
    float* cpv = el2p + NN;
    float* erp = cpv + NN;
    float* dsum = erp + NN;
    hipLaunchKernelGGL(gat_prep, dim3(256), dim3(256), 0, stream, X, W, al, ar, HbT, el2p, cpv, erp, out, dsum);
    hipLaunchKernelGGL(gat_main, dim3(1024), dim3(256), 0, stream, A, HbT, el2p, cpv, erp, out, dsum);
    hipLaunchKernelGGL(gat_norm, dim3(512), dim3(256), 0, stream, out, dsum);
}